// Round 4
// baseline (123.205 us; speedup 1.0000x reference)
//
#include <hip/hip_runtime.h>

#define N_ANGLES 180
#define IMG 256
#define SPAD 363            // ceil(sqrt(2)*256)
#define PB 53               // pad_before = (363-256)//2
#define BATCH 2
#define TOTAL (BATCH * N_ANGLES * SPAD)   // 130680 output elements
#define RSPLIT 2            // r-residue classes per output (lane pairs)

// 32x32 LDS-tiled transpose: imgT[b][x][y] = img[b][y][x]
__global__ __launch_bounds__(256) void transpose_kernel(const float* __restrict__ img,
                                                        float* __restrict__ imgT) {
    __shared__ float tile[32][33];
    const int b  = blockIdx.z;
    const int tx = blockIdx.x * 32;
    const int ty = blockIdx.y * 32;
    const int lx = threadIdx.x & 31;
    const int l8 = threadIdx.x >> 5;       // 0..7
    const float* ib = img  + b * IMG * IMG;
    float*       ob = imgT + b * IMG * IMG;
#pragma unroll
    for (int i = 0; i < 4; ++i) {
        const int ly = l8 + i * 8;
        tile[ly][lx] = ib[(ty + ly) * IMG + tx + lx];
    }
    __syncthreads();
#pragma unroll
    for (int i = 0; i < 4; ++i) {
        const int ly = l8 + i * 8;
        ob[(tx + ly) * IMG + ty + lx] = tile[lx][ly];
    }
}

// Per-sample body. CHECKED=true applies the reference's zero-masking; the
// unchecked variant runs only where the clip model guarantees all 4 taps
// are inside the original 256x256 region (>=1px margin vs <=1e-3px model err).
// wx == fract(ix) == ix - floor(ix) bit-exactly (ix >= 51 > 0 in all executed
// ranges), and (int)ix == floor(ix) for ix >= 0.
#define SAMPLE(r, CHECKED)                                                     \
    {                                                                          \
        const float lr  = fmaf((float)(r), d, -1.0f);                          \
        const float ix  = fmaf(fA, lr, gA);                                    \
        const float iy  = fmaf(fB, lr, gB);                                    \
        const float wx  = ix - floorf(ix);   /* v_fract_f32 */                 \
        const float wy  = iy - floorf(iy);                                     \
        const int   xi  = (int)ix;                                             \
        const int   yi  = (int)iy;                                             \
        float v00, v01, v10, v11;                                              \
        if (CHECKED) {                                                         \
            const int xA = xi - PB, yA = yi - PB;                              \
            const bool vx0 = (unsigned)xA       < (unsigned)IMG;               \
            const bool vx1 = (unsigned)(xA + 1) < (unsigned)IMG;               \
            const bool vy0 = (unsigned)yA       < (unsigned)IMG;               \
            const bool vy1 = (unsigned)(yA + 1) < (unsigned)IMG;               \
            const float* rp = base + yA * IMG + xA;                            \
            v00 = (vx0 && vy0) ? rp[0]       : 0.0f;                           \
            v01 = (vx1 && vy0) ? rp[1]       : 0.0f;                           \
            v10 = (vx0 && vy1) ? rp[IMG]     : 0.0f;                           \
            v11 = (vx1 && vy1) ? rp[IMG + 1] : 0.0f;                           \
        } else {                                                               \
            const float* rp = base + (yi * IMG + xi - (PB * IMG + PB));        \
            v00 = rp[0]; v01 = rp[1]; v10 = rp[IMG]; v11 = rp[IMG + 1];        \
        }                                                                      \
        const float omwx = 1.0f - wx;                                          \
        const float omwy = 1.0f - wy;                                          \
        const float top  = fmaf(v01, wx, v00 * omwx);                          \
        const float bot  = fmaf(v11, wx, v10 * omwx);                          \
        acc = fmaf(bot, wy, fmaf(top, omwy, acc));                             \
    }

template <bool HAVE_T>
__global__ __launch_bounds__(256) void radon_kernel(const float* __restrict__ img,
                                                    const float* __restrict__ imgT,
                                                    float* __restrict__ out) {
    const int gid = blockIdx.x * 256 + threadIdx.x;
    const int o = gid >> 1;        // output element (lane pairs share one output)
    const int p = gid & 1;         // r-residue class mod 2
    if (o >= TOTAL) return;        // pair-aligned: both lanes of a pair exit together

    // o = (b*N_ANGLES + a)*SPAD + t  (consecutive o -> consecutive t: a wave's
    // 64 samples form a 32t x 2r footprint, ~2-3 image rows after transpose)
    const int t  = o % SPAD;
    const int ba = o / SPAD;
    const int a  = ba % N_ANGLES;
    const int b  = ba / N_ANGLES;

    const float theta = (float)a * 0.017453292519943295f;  // float32(pi/180)
    float s, c;
    sincosf(theta, &s, &c);

    const float d  = 2.0f / 362.0f;
    const float lt = fmaf((float)t, d, -1.0f);      // x = lin[t]
    const float ct  = c * lt;                       // cos*x
    const float mst = -s * lt;                      // -sin*x

    // Transposed mode for steep angles (|s|>|c|): bilinear sampling is exactly
    // symmetric under (x<->y, wx<->wy); hoist the swap into coefficients so the
    // inner loop is identical. Caps the slope of the wave's sample line at
    // <=0.707 in the contiguous axis -> fewer cache lines per gather.
    const bool useT = HAVE_T && (s > fabsf(c));
    const float sA = useT ? c   : s;     // ix_used(r) = (sA*lr + cA + 1) * 181
    const float cA = useT ? mst : ct;
    const float sB = useT ? s   : c;     // iy_used(r) = (sB*lr + cB + 1) * 181
    const float cB = useT ? ct  : mst;
    const float* __restrict__ base = (useT ? imgT : img) + b * (IMG * IMG);

    // fold to single-fma form: ix = fmaf(fA, lr, gA)  (<=1e-4 px vs reference)
    const float fA = sA * 181.0f;
    const float gA = (cA + 1.0f) * 181.0f;
    const float fB = sB * 181.0f;
    const float gB = (cB + 1.0f) * 181.0f;

    // linear model over integer r: value = v0 + r*dv  (lr(0) = -1 exactly)
    const float v0A = fmaf(fA, -1.0f, gA), dvA = fA * d;
    const float v0B = fmaf(fB, -1.0f, gB), dvB = fB * d;

    // intersect { r : v0+r*dv in [lo,hi] } into [rlo,rhi]
    auto clip = [](float v0, float dv, float lo, float hi, float& rlo, float& rhi) {
        if (fabsf(dv) < 1e-5f) {
            if (v0 < lo || v0 > hi) { rlo = 363.0f; rhi = -1.0f; }
        } else {
            const float r0 = (lo - v0) / dv;
            const float r1 = (hi - v0) / dv;
            rlo = fmaxf(rlo, fminf(r0, r1));
            rhi = fminf(rhi, fmaxf(r0, r1));
        }
    };

    // "any tap nonzero" range (exact: ix in [52,308]; margins only ADD zeros)
    float rloA = 0.0f, rhiA = 362.0f;
    clip(v0A, dvA, 51.0f, 310.0f, rloA, rhiA);
    clip(v0B, dvB, 51.0f, 310.0f, rloA, rhiA);
    const int rmin = max(0,   (int)floorf(rloA));
    const int rmax = min(362, (int)ceilf(rhiA));

    // "all 4 taps in-bounds" range (exact: ix in [53,307]; shrunk by 1px margin)
    float rloI = (float)rmin, rhiI = (float)rmax;
    clip(v0A, dvA, 54.0f, 307.0f, rloI, rhiI);
    clip(v0B, dvB, 54.0f, 307.0f, rloI, rhiI);
    int rin_lo = (int)ceilf(rloI);
    int rin_hi = (int)floorf(rhiI);
    if (rin_lo < rmin) rin_lo = rmin;
    if (rin_hi > rmax) rin_hi = rmax;
    if (rin_lo > rin_hi) { rin_lo = rmax + 1; rin_hi = rmax; }  // no interior

    float acc = 0.0f;
    // lane p covers r ≡ p (mod 2) within each disjoint sub-range
    for (int r = rmin + ((p - rmin) & (RSPLIT - 1)); r < rin_lo; r += RSPLIT)
        SAMPLE(r, true);
#pragma unroll 2
    for (int r = rin_lo + ((p - rin_lo) & (RSPLIT - 1)); r <= rin_hi; r += RSPLIT)
        SAMPLE(r, false);
    for (int r = rin_hi + 1 + ((p - rin_hi - 1) & (RSPLIT - 1)); r <= rmax; r += RSPLIT)
        SAMPLE(r, true);

    // reduce the 2 r-residue partials (lane pairs 2o, 2o+1 are adjacent)
    acc += __shfl_xor(acc, 1);

    if (p == 0) {
        // out shape (B,1,SPAD,N_ANGLES): out[b][0][t][a]
        out[(b * SPAD + t) * N_ANGLES + a] = acc;
    }
}

extern "C" void kernel_launch(void* const* d_in, const int* in_sizes, int n_in,
                              void* d_out, int out_size, void* d_ws, size_t ws_size,
                              hipStream_t stream) {
    const float* img = (const float*)d_in[0];
    float* out = (float*)d_out;
    float* imgT = (float*)d_ws;
    const bool haveT = ws_size >= (size_t)(BATCH * IMG * IMG * sizeof(float));

    const int threads = TOTAL * RSPLIT;              // 261360
    const int blocks = (threads + 255) / 256;        // 1021

    if (haveT) {
        transpose_kernel<<<dim3(8, 8, 2), 256, 0, stream>>>(img, imgT);
        radon_kernel<true><<<blocks, 256, 0, stream>>>(img, imgT, out);
    } else {
        radon_kernel<false><<<blocks, 256, 0, stream>>>(img, nullptr, out);
    }
}

// Round 5
// 95.676 us; speedup vs baseline: 1.2877x; 1.2877x over previous
//
#include <hip/hip_runtime.h>

#define N_ANGLES 180
#define IMG 256
#define SPAD 363            // ceil(sqrt(2)*256)
#define PB 53               // pad_before = (363-256)//2
#define BATCH 2
#define TOTAL (BATCH * N_ANGLES * SPAD)   // 130680 output elements
#define RSPLIT 4            // r-residue classes per output

// ---- quad-gather table: Q[y][x] = (v(y,x), v(y,x+1), v(y+1,x), v(y+1,x+1)),
// v = image value or 0 outside [0,256)^2. Border QB covers clip slack (<=1.01 px
// from floor/ceil of the ray range ends + fp rounding in the range divide).
#define QB 6
#define QDIM (IMG + 2 * QB)              // 268
#define QELEMS (QDIM * QDIM)             // 71824
#define NTAB (2 * BATCH)                 // [orientation][batch]
#define COFF ((QB - PB) * (QDIM + 1))    // folds (+QB, -PB) into one constant

__global__ __launch_bounds__(256) void prep_quad(const float* __restrict__ img,
                                                 float4* __restrict__ quad) {
    const int e = blockIdx.x * 256 + threadIdx.x;
    if (e >= NTAB * QELEMS) return;
    const int xq = e % QDIM;
    const int t2 = e / QDIM;
    const int yq = t2 % QDIM;
    const int tb = t2 / QDIM;            // v*BATCH + b
    const int b  = tb & (BATCH - 1);
    const int v  = tb >> 1;              // 0 = normal, 1 = transposed
    const int x = xq - QB, y = yq - QB;
    const float* ib = img + b * (IMG * IMG);
    auto val = [&](int yy, int xx) -> float {
        if ((unsigned)yy >= (unsigned)IMG || (unsigned)xx >= (unsigned)IMG) return 0.0f;
        return v ? ib[xx * IMG + yy]     // QT[y][x] = img[x][y]
                 : ib[yy * IMG + xx];
    };
    float4 q;
    q.x = val(y, x);     q.y = val(y, x + 1);
    q.z = val(y + 1, x); q.w = val(y + 1, x + 1);
    quad[e] = q;
}

__global__ __launch_bounds__(256) void radon_quad(const float4* __restrict__ quad,
                                                  float* __restrict__ out) {
    const int gid = blockIdx.x * 256 + threadIdx.x;
    const int o = gid >> 2;        // output element (4 lanes per output)
    const int p = gid & 3;         // r-residue class mod 4
    if (o >= TOTAL) return;        // quad-aligned exit

    // o = (b*N_ANGLES + a)*SPAD + t  (consecutive o -> consecutive t: a wave's
    // samples form a 16t x 4r footprint -> few cache lines after slope capping)
    const int t  = o % SPAD;
    const int ba = o / SPAD;
    const int a  = ba % N_ANGLES;
    const int b  = ba / N_ANGLES;

    const float theta = (float)a * 0.017453292519943295f;  // float32(pi/180)
    float s, c;
    sincosf(theta, &s, &c);

    const float d  = 2.0f / 362.0f;
    const float lt = fmaf((float)t, d, -1.0f);      // x = lin[t]
    const float ct  = c * lt;                       // cos*x
    const float mst = -s * lt;                      // -sin*x

    // steep angles (s > |c|): sample the transposed table with (x,y)/(wx,wy)
    // swapped — bilinear is exactly symmetric; caps the gather slope at 0.707.
    const bool useT = (s > fabsf(c));
    const float sA = useT ? c   : s;     // ix(r) = (sA*lr + cA + 1) * 181
    const float cA = useT ? mst : ct;
    const float sB = useT ? s   : c;     // iy(r) = (sB*lr + cB + 1) * 181
    const float cB = useT ? ct  : mst;
    const float4* __restrict__ qt = quad + ((useT ? BATCH : 0) + b) * QELEMS;

    // exact linear model driving BOTH the clip and the loop:
    //   ix(r) = v0A + r * dvA   (deviation vs reference <= ~3e-5 px)
    const float fA = sA * 181.0f, gA = (cA + 1.0f) * 181.0f;
    const float fB = sB * 181.0f, gB = (cB + 1.0f) * 181.0f;
    const float v0A = fmaf(fA, -1.0f, gA), dvA = fA * d * 181.0f;  // NOTE: see below
    const float v0B = fmaf(fB, -1.0f, gB), dvB = fB * d * 181.0f;
    // dvA must be fA*d (per-r step of lr) — fix: lr step is d, ix step is fA*d.
    // (kept explicit to avoid silent algebra slips)
    const float stepA = fA * d;
    const float stepB = fB * d;

    // intersect { r : v0 + r*step in [lo,hi] }
    float rlo = 0.0f, rhi = 362.0f;
    {
        const float lo = 51.0f, hi = 310.0f;   // exact nonzero range is [52,309)
        if (fabsf(stepA) < 1e-5f) {
            if (v0A < lo || v0A > hi) { rlo = 363.0f; rhi = -1.0f; }
        } else {
            const float r0 = (lo - v0A) / stepA;
            const float r1 = (hi - v0A) / stepA;
            rlo = fmaxf(rlo, fminf(r0, r1));
            rhi = fminf(rhi, fmaxf(r0, r1));
        }
        if (fabsf(stepB) < 1e-5f) {
            if (v0B < lo || v0B > hi) { rlo = 363.0f; rhi = -1.0f; }
        } else {
            const float r0 = (lo - v0B) / stepB;
            const float r1 = (hi - v0B) / stepB;
            rlo = fmaxf(rlo, fminf(r0, r1));
            rhi = fminf(rhi, fmaxf(r0, r1));
        }
    }
    const int rmin = max(0,   (int)floorf(rlo));
    const int rmax = min(362, (int)ceilf(rhi));
    // executed ix in [51-1.01, 310+1.01] -> xi in [49,311] -> table idx in-bounds
    // (QB=6 border: min idx 538, max idx 71016, both inside [0,71824)).

    float acc = 0.0f;
#pragma unroll 2
    for (int r = rmin + ((p - rmin) & 3); r <= rmax; r += RSPLIT) {
        const float rf = (float)r;
        const float ix = fmaf(rf, stepA, v0A);
        const float iy = fmaf(rf, stepB, v0B);
        const float wx = ix - floorf(ix);       // v_fract (ix > 0 always)
        const float wy = iy - floorf(iy);
        const int   xi = (int)ix;               // trunc == floor (positive)
        const int   yi = (int)iy;
        const float4 q = qt[yi * QDIM + xi + COFF];
        const float omwx = 1.0f - wx;
        const float omwy = 1.0f - wy;
        const float top = fmaf(q.y, wx, q.x * omwx);
        const float bot = fmaf(q.w, wx, q.z * omwx);
        acc = fmaf(bot, wy, fmaf(top, omwy, acc));
    }

    // reduce the 4 r-residue partials (lanes o*4+0..3 form an aligned quad)
    acc += __shfl_xor(acc, 1);
    acc += __shfl_xor(acc, 2);

    if (p == 0) {
        // out shape (B,1,SPAD,N_ANGLES): out[b][0][t][a]
        out[(b * SPAD + t) * N_ANGLES + a] = acc;
    }
}

// ---------------- fallback path (validated round-4 kernel) ----------------

__global__ __launch_bounds__(256) void transpose_kernel(const float* __restrict__ img,
                                                        float* __restrict__ imgT) {
    __shared__ float tile[32][33];
    const int b  = blockIdx.z;
    const int tx = blockIdx.x * 32;
    const int ty = blockIdx.y * 32;
    const int lx = threadIdx.x & 31;
    const int l8 = threadIdx.x >> 5;
    const float* ib = img  + b * IMG * IMG;
    float*       ob = imgT + b * IMG * IMG;
#pragma unroll
    for (int i = 0; i < 4; ++i) {
        const int ly = l8 + i * 8;
        tile[ly][lx] = ib[(ty + ly) * IMG + tx + lx];
    }
    __syncthreads();
#pragma unroll
    for (int i = 0; i < 4; ++i) {
        const int ly = l8 + i * 8;
        ob[(tx + ly) * IMG + ty + lx] = tile[lx][ly];
    }
}

#define SAMPLE(r, CHECKED)                                                     \
    {                                                                          \
        const float lr  = fmaf((float)(r), d, -1.0f);                          \
        const float ix  = fmaf(fA, lr, gA);                                    \
        const float iy  = fmaf(fB, lr, gB);                                    \
        const float wx  = ix - floorf(ix);                                     \
        const float wy  = iy - floorf(iy);                                     \
        const int   xi  = (int)ix;                                             \
        const int   yi  = (int)iy;                                             \
        float v00, v01, v10, v11;                                              \
        if (CHECKED) {                                                         \
            const int xA = xi - PB, yA = yi - PB;                              \
            const bool vx0 = (unsigned)xA       < (unsigned)IMG;               \
            const bool vx1 = (unsigned)(xA + 1) < (unsigned)IMG;               \
            const bool vy0 = (unsigned)yA       < (unsigned)IMG;               \
            const bool vy1 = (unsigned)(yA + 1) < (unsigned)IMG;               \
            const float* rp = base + yA * IMG + xA;                            \
            v00 = (vx0 && vy0) ? rp[0]       : 0.0f;                           \
            v01 = (vx1 && vy0) ? rp[1]       : 0.0f;                           \
            v10 = (vx0 && vy1) ? rp[IMG]     : 0.0f;                           \
            v11 = (vx1 && vy1) ? rp[IMG + 1] : 0.0f;                           \
        } else {                                                               \
            const float* rp = base + (yi * IMG + xi - (PB * IMG + PB));        \
            v00 = rp[0]; v01 = rp[1]; v10 = rp[IMG]; v11 = rp[IMG + 1];        \
        }                                                                      \
        const float omwx = 1.0f - wx;                                          \
        const float omwy = 1.0f - wy;                                          \
        const float top  = fmaf(v01, wx, v00 * omwx);                          \
        const float bot  = fmaf(v11, wx, v10 * omwx);                          \
        acc = fmaf(bot, wy, fmaf(top, omwy, acc));                             \
    }

template <bool HAVE_T>
__global__ __launch_bounds__(256) void radon_kernel(const float* __restrict__ img,
                                                    const float* __restrict__ imgT,
                                                    float* __restrict__ out) {
    const int gid = blockIdx.x * 256 + threadIdx.x;
    const int o = gid >> 1;
    const int p = gid & 1;
    if (o >= TOTAL) return;

    const int t  = o % SPAD;
    const int ba = o / SPAD;
    const int a  = ba % N_ANGLES;
    const int b  = ba / N_ANGLES;

    const float theta = (float)a * 0.017453292519943295f;
    float s, c;
    sincosf(theta, &s, &c);

    const float d  = 2.0f / 362.0f;
    const float lt = fmaf((float)t, d, -1.0f);
    const float ct  = c * lt;
    const float mst = -s * lt;

    const bool useT = HAVE_T && (s > fabsf(c));
    const float sA = useT ? c   : s;
    const float cA = useT ? mst : ct;
    const float sB = useT ? s   : c;
    const float cB = useT ? ct  : mst;
    const float* __restrict__ base = (useT ? imgT : img) + b * (IMG * IMG);

    const float fA = sA * 181.0f;
    const float gA = (cA + 1.0f) * 181.0f;
    const float fB = sB * 181.0f;
    const float gB = (cB + 1.0f) * 181.0f;

    const float v0A = fmaf(fA, -1.0f, gA), dvA = fA * d;
    const float v0B = fmaf(fB, -1.0f, gB), dvB = fB * d;

    auto clip = [](float v0, float dv, float lo, float hi, float& rlo, float& rhi) {
        if (fabsf(dv) < 1e-5f) {
            if (v0 < lo || v0 > hi) { rlo = 363.0f; rhi = -1.0f; }
        } else {
            const float r0 = (lo - v0) / dv;
            const float r1 = (hi - v0) / dv;
            rlo = fmaxf(rlo, fminf(r0, r1));
            rhi = fminf(rhi, fmaxf(r0, r1));
        }
    };

    float rloA = 0.0f, rhiA = 362.0f;
    clip(v0A, dvA, 51.0f, 310.0f, rloA, rhiA);
    clip(v0B, dvB, 51.0f, 310.0f, rloA, rhiA);
    const int rmin = max(0,   (int)floorf(rloA));
    const int rmax = min(362, (int)ceilf(rhiA));

    float rloI = (float)rmin, rhiI = (float)rmax;
    clip(v0A, dvA, 54.0f, 307.0f, rloI, rhiI);
    clip(v0B, dvB, 54.0f, 307.0f, rloI, rhiI);
    int rin_lo = (int)ceilf(rloI);
    int rin_hi = (int)floorf(rhiI);
    if (rin_lo < rmin) rin_lo = rmin;
    if (rin_hi > rmax) rin_hi = rmax;
    if (rin_lo > rin_hi) { rin_lo = rmax + 1; rin_hi = rmax; }

    float acc = 0.0f;
    for (int r = rmin + ((p - rmin) & 1); r < rin_lo; r += 2)
        SAMPLE(r, true);
#pragma unroll 2
    for (int r = rin_lo + ((p - rin_lo) & 1); r <= rin_hi; r += 2)
        SAMPLE(r, false);
    for (int r = rin_hi + 1 + ((p - rin_hi - 1) & 1); r <= rmax; r += 2)
        SAMPLE(r, true);

    acc += __shfl_xor(acc, 1);

    if (p == 0) {
        out[(b * SPAD + t) * N_ANGLES + a] = acc;
    }
}

extern "C" void kernel_launch(void* const* d_in, const int* in_sizes, int n_in,
                              void* d_out, int out_size, void* d_ws, size_t ws_size,
                              hipStream_t stream) {
    const float* img = (const float*)d_in[0];
    float* out = (float*)d_out;

    const size_t needQ = (size_t)NTAB * QELEMS * sizeof(float4);   // ~4.6 MB
    if (ws_size >= needQ) {
        float4* quad = (float4*)d_ws;
        prep_quad<<<(NTAB * QELEMS + 255) / 256, 256, 0, stream>>>(img, quad);
        const int threads = TOTAL * RSPLIT;          // 522720
        radon_quad<<<(threads + 255) / 256, 256, 0, stream>>>(quad, out);
    } else if (ws_size >= (size_t)(BATCH * IMG * IMG * sizeof(float))) {
        float* imgT = (float*)d_ws;
        transpose_kernel<<<dim3(8, 8, 2), 256, 0, stream>>>(img, imgT);
        const int threads = TOTAL * 2;
        radon_kernel<true><<<(threads + 255) / 256, 256, 0, stream>>>(img, imgT, out);
    } else {
        const int threads = TOTAL * 2;
        radon_kernel<false><<<(threads + 255) / 256, 256, 0, stream>>>(img, nullptr, out);
    }
}

// Round 12
// 95.272 us; speedup vs baseline: 1.2932x; 1.0042x over previous
//
#include <hip/hip_runtime.h>

#define N_ANGLES 180
#define IMG 256
#define SPAD 363            // ceil(sqrt(2)*256)
#define PB 53               // pad_before = (363-256)//2
#define BATCH 2
#define TOTAL (BATCH * N_ANGLES * SPAD)   // 130680 output elements
#define RSPLIT 4            // r-residue classes per output
#define NBLK ((TOTAL + 63) / 64)          // 2043 work blocks (64 outputs each)
#define NPAD 2048                         // padded grid for the XCD swizzle

// ---- quad-gather table: Q[y][x] = (v(y,x), v(y,x+1), v(y+1,x), v(y+1,x+1)),
// v = image value or 0 outside [0,256)^2. Border QB covers clip slack.
#define QB 6
#define QDIM (IMG + 2 * QB)              // 268
#define QELEMS (QDIM * QDIM)             // 71824
#define NTAB (2 * BATCH)                 // [orientation][batch]
#define COFF ((QB - PB) * (QDIM + 1))    // folds (+QB, -PB) into one constant

__global__ __launch_bounds__(256) void prep_quad(const float* __restrict__ img,
                                                 float4* __restrict__ quad) {
    const int e = blockIdx.x * 256 + threadIdx.x;
    if (e >= NTAB * QELEMS) return;
    const int xq = e % QDIM;
    const int t2 = e / QDIM;
    const int yq = t2 % QDIM;
    const int tb = t2 / QDIM;            // v*BATCH + b
    const int b  = tb & (BATCH - 1);
    const int v  = tb >> 1;              // 0 = normal, 1 = transposed
    const int x = xq - QB, y = yq - QB;
    const float* ib = img + b * (IMG * IMG);
    auto val = [&](int yy, int xx) -> float {
        if ((unsigned)yy >= (unsigned)IMG || (unsigned)xx >= (unsigned)IMG) return 0.0f;
        return v ? ib[xx * IMG + yy]     // QT[y][x] = img[x][y]
                 : ib[yy * IMG + xx];
    };
    float4 q;
    q.x = val(y, x);     q.y = val(y, x + 1);
    q.z = val(y + 1, x); q.w = val(y + 1, x + 1);
    quad[e] = q;
}

// one bilinear sample from the quad table into accumulator A
#define SAMP(r, A)                                                             \
    {                                                                          \
        const float rf = (float)(r);                                           \
        const float ix = fmaf(rf, stepA, v0A);                                 \
        const float iy = fmaf(rf, stepB, v0B);                                 \
        const float wx = ix - floorf(ix);       /* v_fract (ix > 0 always) */  \
        const float wy = iy - floorf(iy);                                      \
        const int   xi = (int)ix;               /* trunc == floor (positive)*/ \
        const int   yi = (int)iy;                                              \
        const float4 q = qt[yi * QDIM + xi + COFF];                            \
        const float omwx = 1.0f - wx;                                          \
        const float omwy = 1.0f - wy;                                          \
        const float top = fmaf(q.y, wx, q.x * omwx);                           \
        const float bot = fmaf(q.w, wx, q.z * omwx);                           \
        A = fmaf(bot, wy, fmaf(top, omwy, A));                                 \
    }

__global__ __launch_bounds__(256) void radon_quad(const float4* __restrict__ quad,
                                                  float* __restrict__ out) {
    // XCD-affine swizzle: inverse round-robin so each XCD (blockIdx%8 heuristic)
    // executes one contiguous chunk of the table-grouped work list -> its L2
    // holds mostly ONE 1.15 MB quad table instead of all 4.6 MB.
    const int L  = blockIdx.x;                       // 0..2047
    const int ob = (L & 7) * (NPAD / 8) + (L >> 3);  // bijection on [0,2048)
    if (ob >= NBLK) return;
    const int o = ob * 64 + (threadIdx.x >> 2);      // output element
    const int p = threadIdx.x & 3;                   // r-residue class mod 4
    if (o >= TOTAL) return;                          // all 4 lanes of a quad exit together

    // table-grouped ordering: o = (b*180 + j)*SPAD + t, where
    //   j <  46 -> a = j        (normal,     theta in [0,45])
    //   j <  91 -> a = j + 89   (normal,     theta in [135,179])
    //   j >= 91 -> a = j - 45   (transposed, theta in [46,134])
    const int t = o % SPAD;
    const int g = o / SPAD;
    const int j = g % 180;
    const int b = g / 180;
    const int a = j + (j < 46 ? 0 : (j < 91 ? 89 : -45));
    const bool useT = (j >= 91);   // layout choice only; both layouts are exact

    const float theta = (float)a * 0.017453292519943295f;  // float32(pi/180)
    float s, c;
    sincosf(theta, &s, &c);

    const float d  = 2.0f / 362.0f;
    const float lt = fmaf((float)t, d, -1.0f);      // x = lin[t]
    const float ct  = c * lt;                       // cos*x
    const float mst = -s * lt;                      // -sin*x

    // steep angles: sample transposed table with (x,y)/(wx,wy) swapped —
    // bilinear is exactly symmetric; caps gather slope at 0.707.
    const float sA = useT ? c   : s;     // ix(r) = (sA*lr + cA + 1) * 181
    const float cA = useT ? mst : ct;
    const float sB = useT ? s   : c;     // iy(r) = (sB*lr + cB + 1) * 181
    const float cB = useT ? ct  : mst;
    const float4* __restrict__ qt = quad + ((useT ? BATCH : 0) + b) * QELEMS;

    // exact linear model driving BOTH the clip and the loop (<= ~3e-5 px dev)
    const float fA = sA * 181.0f, gA = (cA + 1.0f) * 181.0f;
    const float fB = sB * 181.0f, gB = (cB + 1.0f) * 181.0f;
    const float v0A = fmaf(fA, -1.0f, gA), stepA = fA * d;
    const float v0B = fmaf(fB, -1.0f, gB), stepB = fB * d;

    // intersect { r : v0 + r*step in [lo,hi] }
    float rlo = 0.0f, rhi = 362.0f;
    {
        const float lo = 51.0f, hi = 310.0f;   // exact nonzero range is [52,309)
        if (fabsf(stepA) < 1e-5f) {
            if (v0A < lo || v0A > hi) { rlo = 363.0f; rhi = -1.0f; }
        } else {
            const float r0 = (lo - v0A) / stepA;
            const float r1 = (hi - v0A) / stepA;
            rlo = fmaxf(rlo, fminf(r0, r1));
            rhi = fminf(rhi, fmaxf(r0, r1));
        }
        if (fabsf(stepB) < 1e-5f) {
            if (v0B < lo || v0B > hi) { rlo = 363.0f; rhi = -1.0f; }
        } else {
            const float r0 = (lo - v0B) / stepB;
            const float r1 = (hi - v0B) / stepB;
            rlo = fmaxf(rlo, fminf(r0, r1));
            rhi = fminf(rhi, fmaxf(r0, r1));
        }
    }
    const int rmin = max(0,   (int)floorf(rlo));
    const int rmax = min(362, (int)ceilf(rhi));
    // executed ix in [49.99, 311.01] -> table idx stays inside the QB=6 border.

    // lane p covers r ≡ p (mod 4); dual accumulators + stride-8 unroll give
    // 4 independent loads in flight and halve the serial fma chain.
    float acc0 = 0.0f, acc1 = 0.0f;
    int r = rmin + ((p - rmin) & 3);
#pragma unroll 2
    for (; r + 4 <= rmax; r += 8) {
        SAMP(r, acc0);
        SAMP(r + 4, acc1);
    }
    if (r <= rmax) SAMP(r, acc0);
    float acc = acc0 + acc1;

    // reduce the 4 r-residue partials (lanes o*4+0..3 form an aligned quad)
    acc += __shfl_xor(acc, 1);
    acc += __shfl_xor(acc, 2);

    if (p == 0) {
        // out shape (B,1,SPAD,N_ANGLES): out[b][0][t][a]
        out[(b * SPAD + t) * N_ANGLES + a] = acc;
    }
}

// ---------------- fallback path (validated round-4 kernel) ----------------

__global__ __launch_bounds__(256) void transpose_kernel(const float* __restrict__ img,
                                                        float* __restrict__ imgT) {
    __shared__ float tile[32][33];
    const int b  = blockIdx.z;
    const int tx = blockIdx.x * 32;
    const int ty = blockIdx.y * 32;
    const int lx = threadIdx.x & 31;
    const int l8 = threadIdx.x >> 5;
    const float* ib = img  + b * IMG * IMG;
    float*       ob = imgT + b * IMG * IMG;
#pragma unroll
    for (int i = 0; i < 4; ++i) {
        const int ly = l8 + i * 8;
        tile[ly][lx] = ib[(ty + ly) * IMG + tx + lx];
    }
    __syncthreads();
#pragma unroll
    for (int i = 0; i < 4; ++i) {
        const int ly = l8 + i * 8;
        ob[(tx + ly) * IMG + ty + lx] = tile[lx][ly];
    }
}

#define SAMPLE(r, CHECKED)                                                     \
    {                                                                          \
        const float lr  = fmaf((float)(r), d, -1.0f);                          \
        const float ix  = fmaf(fA, lr, gA);                                    \
        const float iy  = fmaf(fB, lr, gB);                                    \
        const float wx  = ix - floorf(ix);                                     \
        const float wy  = iy - floorf(iy);                                     \
        const int   xi  = (int)ix;                                             \
        const int   yi  = (int)iy;                                             \
        float v00, v01, v10, v11;                                              \
        if (CHECKED) {                                                         \
            const int xA = xi - PB, yA = yi - PB;                              \
            const bool vx0 = (unsigned)xA       < (unsigned)IMG;               \
            const bool vx1 = (unsigned)(xA + 1) < (unsigned)IMG;               \
            const bool vy0 = (unsigned)yA       < (unsigned)IMG;               \
            const bool vy1 = (unsigned)(yA + 1) < (unsigned)IMG;               \
            const float* rp = base + yA * IMG + xA;                            \
            v00 = (vx0 && vy0) ? rp[0]       : 0.0f;                           \
            v01 = (vx1 && vy0) ? rp[1]       : 0.0f;                           \
            v10 = (vx0 && vy1) ? rp[IMG]     : 0.0f;                           \
            v11 = (vx1 && vy1) ? rp[IMG + 1] : 0.0f;                           \
        } else {                                                               \
            const float* rp = base + (yi * IMG + xi - (PB * IMG + PB));        \
            v00 = rp[0]; v01 = rp[1]; v10 = rp[IMG]; v11 = rp[IMG + 1];        \
        }                                                                      \
        const float omwx = 1.0f - wx;                                          \
        const float omwy = 1.0f - wy;                                          \
        const float top  = fmaf(v01, wx, v00 * omwx);                          \
        const float bot  = fmaf(v11, wx, v10 * omwx);                          \
        acc = fmaf(bot, wy, fmaf(top, omwy, acc));                             \
    }

template <bool HAVE_T>
__global__ __launch_bounds__(256) void radon_kernel(const float* __restrict__ img,
                                                    const float* __restrict__ imgT,
                                                    float* __restrict__ out) {
    const int gid = blockIdx.x * 256 + threadIdx.x;
    const int o = gid >> 1;
    const int p = gid & 1;
    if (o >= TOTAL) return;

    const int t  = o % SPAD;
    const int ba = o / SPAD;
    const int a  = ba % N_ANGLES;
    const int b  = ba / N_ANGLES;

    const float theta = (float)a * 0.017453292519943295f;
    float s, c;
    sincosf(theta, &s, &c);

    const float d  = 2.0f / 362.0f;
    const float lt = fmaf((float)t, d, -1.0f);
    const float ct  = c * lt;
    const float mst = -s * lt;

    const bool useT = HAVE_T && (s > fabsf(c));
    const float sA = useT ? c   : s;
    const float cA = useT ? mst : ct;
    const float sB = useT ? s   : c;
    const float cB = useT ? ct  : mst;
    const float* __restrict__ base = (useT ? imgT : img) + b * (IMG * IMG);

    const float fA = sA * 181.0f;
    const float gA = (cA + 1.0f) * 181.0f;
    const float fB = sB * 181.0f;
    const float gB = (cB + 1.0f) * 181.0f;

    const float v0A = fmaf(fA, -1.0f, gA), dvA = fA * d;
    const float v0B = fmaf(fB, -1.0f, gB), dvB = fB * d;

    auto clip = [](float v0, float dv, float lo, float hi, float& rlo, float& rhi) {
        if (fabsf(dv) < 1e-5f) {
            if (v0 < lo || v0 > hi) { rlo = 363.0f; rhi = -1.0f; }
        } else {
            const float r0 = (lo - v0) / dv;
            const float r1 = (hi - v0) / dv;
            rlo = fmaxf(rlo, fminf(r0, r1));
            rhi = fminf(rhi, fmaxf(r0, r1));
        }
    };

    float rloA = 0.0f, rhiA = 362.0f;
    clip(v0A, dvA, 51.0f, 310.0f, rloA, rhiA);
    clip(v0B, dvB, 51.0f, 310.0f, rloA, rhiA);
    const int rmin = max(0,   (int)floorf(rloA));
    const int rmax = min(362, (int)ceilf(rhiA));

    float rloI = (float)rmin, rhiI = (float)rmax;
    clip(v0A, dvA, 54.0f, 307.0f, rloI, rhiI);
    clip(v0B, dvB, 54.0f, 307.0f, rloI, rhiI);
    int rin_lo = (int)ceilf(rloI);
    int rin_hi = (int)floorf(rhiI);
    if (rin_lo < rmin) rin_lo = rmin;
    if (rin_hi > rmax) rin_hi = rmax;
    if (rin_lo > rin_hi) { rin_lo = rmax + 1; rin_hi = rmax; }

    float acc = 0.0f;
    for (int r = rmin + ((p - rmin) & 1); r < rin_lo; r += 2)
        SAMPLE(r, true);
#pragma unroll 2
    for (int r = rin_lo + ((p - rin_lo) & 1); r <= rin_hi; r += 2)
        SAMPLE(r, false);
    for (int r = rin_hi + 1 + ((p - rin_hi - 1) & 1); r <= rmax; r += 2)
        SAMPLE(r, true);

    acc += __shfl_xor(acc, 1);

    if (p == 0) {
        out[(b * SPAD + t) * N_ANGLES + a] = acc;
    }
}

extern "C" void kernel_launch(void* const* d_in, const int* in_sizes, int n_in,
                              void* d_out, int out_size, void* d_ws, size_t ws_size,
                              hipStream_t stream) {
    const float* img = (const float*)d_in[0];
    float* out = (float*)d_out;

    const size_t needQ = (size_t)NTAB * QELEMS * sizeof(float4);   // ~4.6 MB
    if (ws_size >= needQ) {
        float4* quad = (float4*)d_ws;
        prep_quad<<<(NTAB * QELEMS + 255) / 256, 256, 0, stream>>>(img, quad);
        radon_quad<<<NPAD, 256, 0, stream>>>(quad, out);
    } else if (ws_size >= (size_t)(BATCH * IMG * IMG * sizeof(float))) {
        float* imgT = (float*)d_ws;
        transpose_kernel<<<dim3(8, 8, 2), 256, 0, stream>>>(img, imgT);
        const int threads = TOTAL * 2;
        radon_kernel<true><<<(threads + 255) / 256, 256, 0, stream>>>(img, imgT, out);
    } else {
        const int threads = TOTAL * 2;
        radon_kernel<false><<<(threads + 255) / 256, 256, 0, stream>>>(img, nullptr, out);
    }
}

// Round 15
// 91.278 us; speedup vs baseline: 1.3498x; 1.0438x over previous
//
#include <hip/hip_runtime.h>

#define N_ANGLES 180
#define IMG 256
#define SPAD 363            // ceil(sqrt(2)*256)
#define PB 53               // pad_before = (363-256)//2
#define BATCH 2
#define TOTAL (BATCH * N_ANGLES * SPAD)   // 130680 output elements
#define NBLK ((TOTAL + 63) / 64)          // 2043 work blocks (64 outputs each)
#define NPAD 2048                         // padded grid for the XCD swizzle

// ---- quad-gather table: Q[y][x] = (v(y,x), v(y,x+1), v(y+1,x), v(y+1,x+1)),
// v = image value or 0 outside [0,256)^2. Border QB covers clip slack.
#define QB 6
#define QDIM (IMG + 2 * QB)              // 268
#define QELEMS (QDIM * QDIM)             // 71824
#define NTAB (2 * BATCH)                 // [orientation][batch]
#define COFF ((QB - PB) * (QDIM + 1))    // folds (+QB, -PB) into one constant

__global__ __launch_bounds__(256) void prep_quad(const float* __restrict__ img,
                                                 float4* __restrict__ quad) {
    const int e = blockIdx.x * 256 + threadIdx.x;
    if (e >= NTAB * QELEMS) return;
    const int xq = e % QDIM;
    const int t2 = e / QDIM;
    const int yq = t2 % QDIM;
    const int tb = t2 / QDIM;            // v*BATCH + b
    const int b  = tb & (BATCH - 1);
    const int v  = tb >> 1;              // 0 = normal, 1 = transposed
    const int x = xq - QB, y = yq - QB;
    const float* ib = img + b * (IMG * IMG);
    auto val = [&](int yy, int xx) -> float {
        if ((unsigned)yy >= (unsigned)IMG || (unsigned)xx >= (unsigned)IMG) return 0.0f;
        return v ? ib[xx * IMG + yy]     // QT[y][x] = img[x][y]
                 : ib[yy * IMG + xx];
    };
    float4 q;
    q.x = val(y, x);     q.y = val(y, x + 1);
    q.z = val(y + 1, x); q.w = val(y + 1, x + 1);
    quad[e] = q;
}

// one bilinear sample from the quad table into accumulator A
#define SAMP(r, A)                                                             \
    {                                                                          \
        const float rf = (float)(r);                                           \
        const float ix = fmaf(rf, stepA, v0A);                                 \
        const float iy = fmaf(rf, stepB, v0B);                                 \
        const float wx = ix - floorf(ix);       /* v_fract (ix > 0 always) */  \
        const float wy = iy - floorf(iy);                                      \
        const int   xi = (int)ix;               /* trunc == floor (positive)*/ \
        const int   yi = (int)iy;                                              \
        const float4 q = qt[yi * QDIM + xi + COFF];                            \
        const float omwx = 1.0f - wx;                                          \
        const float omwy = 1.0f - wy;                                          \
        const float top = fmaf(q.y, wx, q.x * omwx);                           \
        const float bot = fmaf(q.w, wx, q.z * omwx);                           \
        A = fmaf(bot, wy, fmaf(top, omwy, A));                                 \
    }

__global__ __launch_bounds__(256) void radon_quad(const float4* __restrict__ quad,
                                                  float* __restrict__ out) {
    // XCD-affine swizzle (kept from r12): each XCD works one contiguous chunk
    // of the table-grouped work list.
    const int L  = blockIdx.x;                       // 0..2047
    const int ob = (L & 7) * (NPAD / 8) + (L >> 3);  // bijection on [0,2048)
    if (ob >= NBLK) return;
    const int o = ob * 64 + (threadIdx.x >> 2);      // output element
    const int p = threadIdx.x & 3;                   // r-residue class mod 4
    if (o >= TOTAL) return;                          // quad-aligned exit

    // table-grouped ordering: o = (b*180 + j)*SPAD + t, where
    //   j <  46 -> a = j        (normal,     theta in [0,45])
    //   j <  91 -> a = j + 89   (normal,     theta in [135,179])
    //   j >= 91 -> a = j - 45   (transposed, theta in [46,134])
    const int t = o % SPAD;
    const int g = o / SPAD;
    const int j = g % 180;
    const int b = g / 180;
    const int a = j + (j < 46 ? 0 : (j < 91 ? 89 : -45));
    const bool useT = (j >= 91);   // layout choice only; both layouts are exact

    const float theta = (float)a * 0.017453292519943295f;  // float32(pi/180)
    float s, c;
    sincosf(theta, &s, &c);

    const float d  = 2.0f / 362.0f;
    const float lt = fmaf((float)t, d, -1.0f);      // x = lin[t]
    const float ct  = c * lt;                       // cos*x
    const float mst = -s * lt;                      // -sin*x

    // steep angles: sample transposed table with (x,y)/(wx,wy) swapped —
    // bilinear is exactly symmetric; caps gather slope at 0.707.
    const float sA = useT ? c   : s;     // ix(r) = (sA*lr + cA + 1) * 181
    const float cA = useT ? mst : ct;
    const float sB = useT ? s   : c;     // iy(r) = (sB*lr + cB + 1) * 181
    const float cB = useT ? ct  : mst;
    const float4* __restrict__ qt = quad + ((useT ? BATCH : 0) + b) * QELEMS;

    // exact linear model driving BOTH the clip and the loop (<= ~3e-5 px dev)
    const float fA = sA * 181.0f, gA = (cA + 1.0f) * 181.0f;
    const float fB = sB * 181.0f, gB = (cB + 1.0f) * 181.0f;
    const float v0A = fmaf(fA, -1.0f, gA), stepA = fA * d;
    const float v0B = fmaf(fB, -1.0f, gB), stepB = fB * d;

    // intersect { r : v0 + r*step in [lo,hi] }
    float rlo = 0.0f, rhi = 362.0f;
    {
        const float lo = 51.0f, hi = 310.0f;   // exact nonzero range is [52,309)
        if (fabsf(stepA) < 1e-5f) {
            if (v0A < lo || v0A > hi) { rlo = 363.0f; rhi = -1.0f; }
        } else {
            const float r0 = (lo - v0A) / stepA;
            const float r1 = (hi - v0A) / stepA;
            rlo = fmaxf(rlo, fminf(r0, r1));
            rhi = fminf(rhi, fmaxf(r0, r1));
        }
        if (fabsf(stepB) < 1e-5f) {
            if (v0B < lo || v0B > hi) { rlo = 363.0f; rhi = -1.0f; }
        } else {
            const float r0 = (lo - v0B) / stepB;
            const float r1 = (hi - v0B) / stepB;
            rlo = fmaxf(rlo, fminf(r0, r1));
            rhi = fminf(rhi, fmaxf(r0, r1));
        }
    }
    const int rmin = max(0,   (int)floorf(rlo));
    const int rmax = min(362, (int)ceilf(rhi));
    // executed ix in [49.99, 311.01] -> table idx stays inside the QB=6 border.

    // lane p covers r ≡ p (mod 4). FOUR independent accumulators at stride 16:
    // 8 loads in flight per lane (r12 counters: throughput == inflight/latency,
    // so doubling MLP is the direct lever; 41.7 µs was 32 waves x 4 loads).
    float a0 = 0.0f, a1 = 0.0f, a2 = 0.0f, a3 = 0.0f;
    int r = rmin + ((p - rmin) & 3);
    for (; r + 12 <= rmax; r += 16) {
        SAMP(r,      a0);
        SAMP(r + 4,  a1);
        SAMP(r + 8,  a2);
        SAMP(r + 12, a3);
    }
    if (r     <= rmax) SAMP(r,     a0);
    if (r + 4 <= rmax) SAMP(r + 4, a1);
    if (r + 8 <= rmax) SAMP(r + 8, a2);
    float acc = (a0 + a1) + (a2 + a3);

    // reduce the 4 r-residue partials (lanes o*4+0..3 form an aligned quad)
    acc += __shfl_xor(acc, 1);
    acc += __shfl_xor(acc, 2);

    if (p == 0) {
        // out shape (B,1,SPAD,N_ANGLES): out[b][0][t][a]
        out[(b * SPAD + t) * N_ANGLES + a] = acc;
    }
}

// ---------------- fallback path (validated round-4 kernel) ----------------

__global__ __launch_bounds__(256) void transpose_kernel(const float* __restrict__ img,
                                                        float* __restrict__ imgT) {
    __shared__ float tile[32][33];
    const int b  = blockIdx.z;
    const int tx = blockIdx.x * 32;
    const int ty = blockIdx.y * 32;
    const int lx = threadIdx.x & 31;
    const int l8 = threadIdx.x >> 5;
    const float* ib = img  + b * IMG * IMG;
    float*       ob = imgT + b * IMG * IMG;
#pragma unroll
    for (int i = 0; i < 4; ++i) {
        const int ly = l8 + i * 8;
        tile[ly][lx] = ib[(ty + ly) * IMG + tx + lx];
    }
    __syncthreads();
#pragma unroll
    for (int i = 0; i < 4; ++i) {
        const int ly = l8 + i * 8;
        ob[(tx + ly) * IMG + ty + lx] = tile[lx][ly];
    }
}

#define SAMPLE(r, CHECKED)                                                     \
    {                                                                          \
        const float lr  = fmaf((float)(r), d, -1.0f);                          \
        const float ix  = fmaf(fA, lr, gA);                                    \
        const float iy  = fmaf(fB, lr, gB);                                    \
        const float wx  = ix - floorf(ix);                                     \
        const float wy  = iy - floorf(iy);                                     \
        const int   xi  = (int)ix;                                             \
        const int   yi  = (int)iy;                                             \
        float v00, v01, v10, v11;                                              \
        if (CHECKED) {                                                         \
            const int xA = xi - PB, yA = yi - PB;                              \
            const bool vx0 = (unsigned)xA       < (unsigned)IMG;               \
            const bool vx1 = (unsigned)(xA + 1) < (unsigned)IMG;               \
            const bool vy0 = (unsigned)yA       < (unsigned)IMG;               \
            const bool vy1 = (unsigned)(yA + 1) < (unsigned)IMG;               \
            const float* rp = base + yA * IMG + xA;                            \
            v00 = (vx0 && vy0) ? rp[0]       : 0.0f;                           \
            v01 = (vx1 && vy0) ? rp[1]       : 0.0f;                           \
            v10 = (vx0 && vy1) ? rp[IMG]     : 0.0f;                           \
            v11 = (vx1 && vy1) ? rp[IMG + 1] : 0.0f;                           \
        } else {                                                               \
            const float* rp = base + (yi * IMG + xi - (PB * IMG + PB));        \
            v00 = rp[0]; v01 = rp[1]; v10 = rp[IMG]; v11 = rp[IMG + 1];        \
        }                                                                      \
        const float omwx = 1.0f - wx;                                          \
        const float omwy = 1.0f - wy;                                          \
        const float top  = fmaf(v01, wx, v00 * omwx);                          \
        const float bot  = fmaf(v11, wx, v10 * omwx);                          \
        acc = fmaf(bot, wy, fmaf(top, omwy, acc));                             \
    }

template <bool HAVE_T>
__global__ __launch_bounds__(256) void radon_kernel(const float* __restrict__ img,
                                                    const float* __restrict__ imgT,
                                                    float* __restrict__ out) {
    const int gid = blockIdx.x * 256 + threadIdx.x;
    const int o = gid >> 1;
    const int p = gid & 1;
    if (o >= TOTAL) return;

    const int t  = o % SPAD;
    const int ba = o / SPAD;
    const int a  = ba % N_ANGLES;
    const int b  = ba / N_ANGLES;

    const float theta = (float)a * 0.017453292519943295f;
    float s, c;
    sincosf(theta, &s, &c);

    const float d  = 2.0f / 362.0f;
    const float lt = fmaf((float)t, d, -1.0f);
    const float ct  = c * lt;
    const float mst = -s * lt;

    const bool useT = HAVE_T && (s > fabsf(c));
    const float sA = useT ? c   : s;
    const float cA = useT ? mst : ct;
    const float sB = useT ? s   : c;
    const float cB = useT ? ct  : mst;
    const float* __restrict__ base = (useT ? imgT : img) + b * (IMG * IMG);

    const float fA = sA * 181.0f;
    const float gA = (cA + 1.0f) * 181.0f;
    const float fB = sB * 181.0f;
    const float gB = (cB + 1.0f) * 181.0f;

    const float v0A = fmaf(fA, -1.0f, gA), dvA = fA * d;
    const float v0B = fmaf(fB, -1.0f, gB), dvB = fB * d;

    auto clip = [](float v0, float dv, float lo, float hi, float& rlo, float& rhi) {
        if (fabsf(dv) < 1e-5f) {
            if (v0 < lo || v0 > hi) { rlo = 363.0f; rhi = -1.0f; }
        } else {
            const float r0 = (lo - v0) / dv;
            const float r1 = (hi - v0) / dv;
            rlo = fmaxf(rlo, fminf(r0, r1));
            rhi = fminf(rhi, fmaxf(r0, r1));
        }
    };

    float rloA = 0.0f, rhiA = 362.0f;
    clip(v0A, dvA, 51.0f, 310.0f, rloA, rhiA);
    clip(v0B, dvB, 51.0f, 310.0f, rloA, rhiA);
    const int rmin = max(0,   (int)floorf(rloA));
    const int rmax = min(362, (int)ceilf(rhiA));

    float rloI = (float)rmin, rhiI = (float)rmax;
    clip(v0A, dvA, 54.0f, 307.0f, rloI, rhiI);
    clip(v0B, dvB, 54.0f, 307.0f, rloI, rhiI);
    int rin_lo = (int)ceilf(rloI);
    int rin_hi = (int)floorf(rhiI);
    if (rin_lo < rmin) rin_lo = rmin;
    if (rin_hi > rmax) rin_hi = rmax;
    if (rin_lo > rin_hi) { rin_lo = rmax + 1; rin_hi = rmax; }

    float acc = 0.0f;
    for (int r = rmin + ((p - rmin) & 1); r < rin_lo; r += 2)
        SAMPLE(r, true);
#pragma unroll 2
    for (int r = rin_lo + ((p - rin_lo) & 1); r <= rin_hi; r += 2)
        SAMPLE(r, false);
    for (int r = rin_hi + 1 + ((p - rin_hi - 1) & 1); r <= rmax; r += 2)
        SAMPLE(r, true);

    acc += __shfl_xor(acc, 1);

    if (p == 0) {
        out[(b * SPAD + t) * N_ANGLES + a] = acc;
    }
}

extern "C" void kernel_launch(void* const* d_in, const int* in_sizes, int n_in,
                              void* d_out, int out_size, void* d_ws, size_t ws_size,
                              hipStream_t stream) {
    const float* img = (const float*)d_in[0];
    float* out = (float*)d_out;

    const size_t needQ = (size_t)NTAB * QELEMS * sizeof(float4);   // ~4.6 MB
    if (ws_size >= needQ) {
        float4* quad = (float4*)d_ws;
        prep_quad<<<(NTAB * QELEMS + 255) / 256, 256, 0, stream>>>(img, quad);
        radon_quad<<<NPAD, 256, 0, stream>>>(quad, out);
    } else if (ws_size >= (size_t)(BATCH * IMG * IMG * sizeof(float))) {
        float* imgT = (float*)d_ws;
        transpose_kernel<<<dim3(8, 8, 2), 256, 0, stream>>>(img, imgT);
        const int threads = TOTAL * 2;
        radon_kernel<true><<<(threads + 255) / 256, 256, 0, stream>>>(img, imgT, out);
    } else {
        const int threads = TOTAL * 2;
        radon_kernel<false><<<(threads + 255) / 256, 256, 0, stream>>>(img, nullptr, out);
    }
}